// Round 1
// baseline (164.163 us; speedup 1.0000x reference)
//
#include <hip/hip_runtime.h>

// NGF loss: g = normalized gradient (central diff interior, one-sided at edges),
// loss = 1 - mean( (g0 . g1)^2 ) over all pixels.
// Shapes fixed by setup_inputs(): B=64, C=1, H=512, W=512, fp32.

#define HH 512
#define WW 512
#define W4 (WW / 4)
#define NGF_EPS 1e-10f

__global__ __launch_bounds__(256) void ngf_partial(const float* __restrict__ I0,
                                                   const float* __restrict__ I1,
                                                   float* __restrict__ partials) {
    const int t = blockIdx.x * 256 + threadIdx.x;   // one thread per float4 group
    const int w4   = t & (W4 - 1);                  // W4 = 128
    const int rest = t >> 7;
    const int h    = rest & (HH - 1);
    const int img  = rest >> 9;                     // b index (C=1)
    const int w    = w4 << 2;

    const long long base = (long long)img * (HH * WW) + (long long)h * WW;
    const float* r0 = I0 + base;
    const float* r1 = I1 + base;

    // Row offsets implementing max(h-1,0) / min(h+1,H-1):
    // h=0:   up=h,   down=h+1  -> forward diff x[1]-x[0]
    // h=H-1: up=h-1, down=h    -> backward diff x[H-1]-x[H-2]
    // else:  up=h-1, down=h+1  -> central diff
    const int hu = (h > 0)      ? -WW : 0;
    const int hd = (h < HH - 1) ?  WW : 0;

    const float4 c0 = *(const float4*)(r0 + w);
    const float4 u0 = *(const float4*)(r0 + w + hu);
    const float4 d0 = *(const float4*)(r0 + w + hd);
    const float  l0 = (w > 0)       ? r0[w - 1] : c0.x;   // max(w-1,0)
    const float  q0 = (w + 4 < WW)  ? r0[w + 4] : c0.w;   // min(w+4,W-1)

    const float4 c1 = *(const float4*)(r1 + w);
    const float4 u1 = *(const float4*)(r1 + w + hu);
    const float4 d1 = *(const float4*)(r1 + w + hd);
    const float  l1 = (w > 0)       ? r1[w - 1] : c1.x;
    const float  q1 = (w + 4 < WW)  ? r1[w + 4] : c1.w;

    // g_x = down - up, per lane of the float4
    const float gx0[4] = {d0.x - u0.x, d0.y - u0.y, d0.z - u0.z, d0.w - u0.w};
    const float gx1[4] = {d1.x - u1.x, d1.y - u1.y, d1.z - u1.z, d1.w - u1.w};
    // sliding window for g_y: a[i+2] - a[i]
    const float a0[6] = {l0, c0.x, c0.y, c0.z, c0.w, q0};
    const float a1[6] = {l1, c1.x, c1.y, c1.z, c1.w, q1};

    float s = 0.f;
#pragma unroll
    for (int i = 0; i < 4; ++i) {
        const float gy0 = a0[i + 2] - a0[i];
        const float gy1 = a1[i + 2] - a1[i];
        const float n0  = gx0[i] * gx0[i] + gy0 * gy0 + NGF_EPS;
        const float n1  = gx1[i] * gx1[i] + gy1 * gy1 + NGF_EPS;
        const float dot = (gx0[i] * gx1[i] + gy0 * gy1) * __frsqrt_rn(n0) * __frsqrt_rn(n1);
        s += dot * dot;
    }

    // wave64 reduce
#pragma unroll
    for (int off = 32; off > 0; off >>= 1) s += __shfl_down(s, off, 64);

    __shared__ float lds[4];
    const int wave = threadIdx.x >> 6;
    const int lane = threadIdx.x & 63;
    if (lane == 0) lds[wave] = s;
    __syncthreads();
    if (threadIdx.x == 0)
        partials[blockIdx.x] = lds[0] + lds[1] + lds[2] + lds[3];
}

__global__ __launch_bounds__(256) void ngf_finalize(const float* __restrict__ partials,
                                                    int nparts, float inv_n,
                                                    float* __restrict__ out) {
    float s = 0.f;
    for (int i = threadIdx.x; i < nparts; i += 256) s += partials[i];
#pragma unroll
    for (int off = 32; off > 0; off >>= 1) s += __shfl_down(s, off, 64);

    __shared__ float lds[4];
    const int wave = threadIdx.x >> 6;
    const int lane = threadIdx.x & 63;
    if (lane == 0) lds[wave] = s;
    __syncthreads();
    if (threadIdx.x == 0)
        out[0] = 1.0f - (lds[0] + lds[1] + lds[2] + lds[3]) * inv_n;
}

extern "C" void kernel_launch(void* const* d_in, const int* in_sizes, int n_in,
                              void* d_out, int out_size, void* d_ws, size_t ws_size,
                              hipStream_t stream) {
    const float* I0 = (const float*)d_in[0];
    const float* I1 = (const float*)d_in[1];
    float* partials = (float*)d_ws;

    const int N        = in_sizes[0];        // 64*1*512*512 = 16777216
    const int nthreads = N / 4;              // one thread per 4 pixels
    const int nblocks  = nthreads / 256;     // 16384 blocks, each writes 1 partial

    ngf_partial<<<nblocks, 256, 0, stream>>>(I0, I1, partials);
    ngf_finalize<<<1, 256, 0, stream>>>(partials, nblocks, 1.0f / (float)N,
                                        (float*)d_out);
}

// Round 2
// 144.907 us; speedup vs baseline: 1.1329x; 1.1329x over previous
//
#include <hip/hip_runtime.h>

// NGF loss: g = normalized gradient (central diff interior, one-sided at edges),
// loss = 1 - mean( (g0 . g1)^2 ).
// Shapes fixed by setup_inputs(): B=64, C=1, H=512, W=512, fp32.
//
// R1: 4x4 px tile per thread (16 px), all 28 loads issued up-front for MLP;
//     dot^2/(n0*n1) via one rcp instead of two rsqrt; float4 finalize.

#define HH 512
#define WW 512
#define NGF_EPS 1e-10f

__device__ __forceinline__ float get(const float4& v, int i) {
    return i == 0 ? v.x : i == 1 ? v.y : i == 2 ? v.z : v.w;
}

// threads = B * (H/4) * (W/4) = 64*128*128 = 1,048,576 -> 4096 blocks x 256
__global__ __launch_bounds__(256, 4) void ngf_partial(const float* __restrict__ I0,
                                                      const float* __restrict__ I1,
                                                      float* __restrict__ partials) {
    const int t    = blockIdx.x * 256 + threadIdx.x;
    const int w4   = t & 127;          // col group: w = w4*4
    const int rest = t >> 7;
    const int h4   = rest & 127;       // row group: h0 = h4*4
    const int img  = rest >> 7;        // batch index (C=1)
    const int w    = w4 << 2;
    const int h0   = h4 << 2;

    const float* p0 = I0 + (size_t)img * (HH * WW);
    const float* p1 = I1 + (size_t)img * (HH * WW);

    // Row offsets for rows h0-1 .. h0+4, clamped to [0, H-1]. Clamped-address
    // loads reproduce the reference's forward/central/backward diff exactly.
    int roff[6];
#pragma unroll
    for (int j = 0; j < 6; ++j) {
        int r = h0 - 1 + j;
        r = r < 0 ? 0 : (r > HH - 1 ? HH - 1 : r);
        roff[j] = r * WW;
    }
    const int wl = (w > 0) ? w - 1 : 0;            // max(w-1, 0)
    const int wq = (w + 4 < WW) ? w + 4 : WW - 1;  // min(w+4, W-1)

    // Issue ALL loads before any dependent compute (memory-level parallelism).
    float4 A0[6], A1[6];
#pragma unroll
    for (int j = 0; j < 6; ++j) {
        A0[j] = *(const float4*)(p0 + roff[j] + w);
        A1[j] = *(const float4*)(p1 + roff[j] + w);
    }
    float l0[4], q0[4], l1[4], q1[4];
#pragma unroll
    for (int r = 0; r < 4; ++r) {
        l0[r] = p0[roff[r + 1] + wl];
        q0[r] = p0[roff[r + 1] + wq];
        l1[r] = p1[roff[r + 1] + wl];
        q1[r] = p1[roff[r + 1] + wq];
    }

    float s = 0.f;
#pragma unroll
    for (int r = 0; r < 4; ++r) {
#pragma unroll
        for (int i = 0; i < 4; ++i) {
            // g_x: rows (r-1, r+1) clamped -> A[r], A[r+2]
            const float gx0 = get(A0[r + 2], i) - get(A0[r], i);
            const float gx1 = get(A1[r + 2], i) - get(A1[r], i);
            // g_y: cols (w+i-1, w+i+1) clamped; halo from l/q scalars
            const float am0 = (i == 0) ? l0[r] : get(A0[r + 1], i - 1);
            const float ap0 = (i == 3) ? q0[r] : get(A0[r + 1], i + 1);
            const float am1 = (i == 0) ? l1[r] : get(A1[r + 1], i - 1);
            const float ap1 = (i == 3) ? q1[r] : get(A1[r + 1], i + 1);
            const float gy0 = ap0 - am0;
            const float gy1 = ap1 - am1;
            const float n0 = gx0 * gx0 + gy0 * gy0 + NGF_EPS;
            const float n1 = gx1 * gx1 + gy1 * gy1 + NGF_EPS;
            const float cross = gx0 * gx1 + gy0 * gy1;
            // dot^2 = cross^2 / (n0*n1): one rcp instead of two rsqrt
            s += cross * cross * __frcp_rn(n0 * n1);
        }
    }

    // wave64 reduce -> LDS -> one partial per block
#pragma unroll
    for (int off = 32; off > 0; off >>= 1) s += __shfl_down(s, off, 64);

    __shared__ float lds[4];
    const int wave = threadIdx.x >> 6;
    const int lane = threadIdx.x & 63;
    if (lane == 0) lds[wave] = s;
    __syncthreads();
    if (threadIdx.x == 0)
        partials[blockIdx.x] = lds[0] + lds[1] + lds[2] + lds[3];
}

// 4096 partials: one float4 per thread, 1024 threads, one block.
__global__ __launch_bounds__(1024) void ngf_finalize(const float4* __restrict__ partials,
                                                     float inv_n,
                                                     float* __restrict__ out) {
    const float4 v = partials[threadIdx.x];
    float s = v.x + v.y + v.z + v.w;
#pragma unroll
    for (int off = 32; off > 0; off >>= 1) s += __shfl_down(s, off, 64);

    __shared__ float lds[16];
    const int wave = threadIdx.x >> 6;
    const int lane = threadIdx.x & 63;
    if (lane == 0) lds[wave] = s;
    __syncthreads();
    if (threadIdx.x == 0) {
        float tot = 0.f;
#pragma unroll
        for (int i = 0; i < 16; ++i) tot += lds[i];
        out[0] = 1.0f - tot * inv_n;
    }
}

extern "C" void kernel_launch(void* const* d_in, const int* in_sizes, int n_in,
                              void* d_out, int out_size, void* d_ws, size_t ws_size,
                              hipStream_t stream) {
    const float* I0 = (const float*)d_in[0];
    const float* I1 = (const float*)d_in[1];
    float* partials = (float*)d_ws;

    const int N        = in_sizes[0];          // 16,777,216
    const int nthreads = N / 16;               // 16 px per thread
    const int nblocks  = nthreads / 256;       // 4096

    ngf_partial<<<nblocks, 256, 0, stream>>>(I0, I1, partials);
    ngf_finalize<<<1, 1024, 0, stream>>>((const float4*)partials,
                                         1.0f / (float)N, (float*)d_out);
}

// Round 3
// 143.321 us; speedup vs baseline: 1.1454x; 1.0111x over previous
//
#include <hip/hip_runtime.h>

// NGF loss: g = normalized gradient (central diff interior, one-sided at edges),
// loss = 1 - mean( (g0 . g1)^2 ).
// Shapes fixed by setup_inputs(): B=64, C=1, H=512, W=512, fp32.
//
// R3: 4x4 px tile; ONLY 12 float4 loads per thread (no scalar halo loads).
//     W-halos come from __shfl neighbors; wave-boundary columns exchanged
//     through a 256B LDS buffer; image-edge columns are clamps (reuse own
//     register). asm memory fence pins all loads before compute so the
//     compiler can't sink them (R2 compiled to VGPR=32 => loads serialized).

#define HH 512
#define WW 512
#define NGF_EPS 1e-10f

__device__ __forceinline__ float get(const float4& v, int i) {
    return i == 0 ? v.x : i == 1 ? v.y : i == 2 ? v.z : v.w;
}

// threads = B * (H/4) * (W/4) = 64*128*128 = 1,048,576 -> 4096 blocks x 256
__global__ __launch_bounds__(256) void ngf_partial(const float* __restrict__ I0,
                                                   const float* __restrict__ I1,
                                                   float* __restrict__ partials) {
    const int t    = blockIdx.x * 256 + threadIdx.x;
    const int w4   = t & 127;          // col group: w = w4*4   (128 groups = full row)
    const int rest = t >> 7;
    const int h4   = rest & 127;       // row group: h0 = h4*4
    const int img  = rest >> 7;        // batch index (C=1); constant within a block
    const int w    = w4 << 2;
    const int h0   = h4 << 2;

    const float* p0 = I0 + (size_t)img * (HH * WW);
    const float* p1 = I1 + (size_t)img * (HH * WW);

    // Rows h0-1 .. h0+4 clamped to [0, H-1] -> forward/central/backward diff.
    int roff[6];
#pragma unroll
    for (int j = 0; j < 6; ++j) {
        int r = h0 - 1 + j;
        r = r < 0 ? 0 : (r > HH - 1 ? HH - 1 : r);
        roff[j] = r * WW;
    }

    // All 12 float4 loads issued before any compute; fence stops sinking.
    float4 A0[6], A1[6];
#pragma unroll
    for (int j = 0; j < 6; ++j) A0[j] = *(const float4*)(p0 + roff[j] + w);
#pragma unroll
    for (int j = 0; j < 6; ++j) A1[j] = *(const float4*)(p1 + roff[j] + w);
    asm volatile("" ::: "memory");

    // Wave-boundary column exchange. Within a wave, lane +-1 <=> w4 +-1.
    // Wave 0/2 cover w4 0..63, wave 1/3 cover 64..127 (same h-row-group pairs
    // {0,1} and {2,3}). Lane 0 of waves 1,3 needs lane 63 of waves 0,2 and
    // vice versa -> tiny LDS buffer; image edges (w4==0/127) are clamps.
    __shared__ float eL[4][4][2];   // [wave][row][img0/1]: lane 0's c.x
    __shared__ float eR[4][4][2];   // [wave][row][img0/1]: lane 63's c.w
    const int wave = threadIdx.x >> 6;
    const int lane = threadIdx.x & 63;
    if (lane == 0) {
#pragma unroll
        for (int r = 0; r < 4; ++r) { eL[wave][r][0] = A0[r + 1].x; eL[wave][r][1] = A1[r + 1].x; }
    }
    if (lane == 63) {
#pragma unroll
        for (int r = 0; r < 4; ++r) { eR[wave][r][0] = A0[r + 1].w; eR[wave][r][1] = A1[r + 1].w; }
    }
    __syncthreads();

    float s = 0.f;
#pragma unroll
    for (int r = 0; r < 4; ++r) {
        const float4 c0 = A0[r + 1], c1 = A1[r + 1];
        // left neighbor scalar (w-1, clamped)
        float L0 = __shfl_up(c0.w, 1, 64);
        float L1 = __shfl_up(c1.w, 1, 64);
        if (lane == 0) {
            if (w4 == 0) { L0 = c0.x; L1 = c1.x; }                 // clamp at w=0
            else         { L0 = eR[wave - 1][r][0]; L1 = eR[wave - 1][r][1]; }
        }
        // right neighbor scalar (w+4, clamped)
        float R0 = __shfl_down(c0.x, 1, 64);
        float R1 = __shfl_down(c1.x, 1, 64);
        if (lane == 63) {
            if (w4 == 127) { R0 = c0.w; R1 = c1.w; }               // clamp at w=W-1
            else           { R0 = eL[wave + 1][r][0]; R1 = eL[wave + 1][r][1]; }
        }
#pragma unroll
        for (int i = 0; i < 4; ++i) {
            const float gx0 = get(A0[r + 2], i) - get(A0[r], i);
            const float gx1 = get(A1[r + 2], i) - get(A1[r], i);
            const float am0 = (i == 0) ? L0 : get(c0, i - 1);
            const float ap0 = (i == 3) ? R0 : get(c0, i + 1);
            const float am1 = (i == 0) ? L1 : get(c1, i - 1);
            const float ap1 = (i == 3) ? R1 : get(c1, i + 1);
            const float gy0 = ap0 - am0;
            const float gy1 = ap1 - am1;
            const float n0 = gx0 * gx0 + gy0 * gy0 + NGF_EPS;
            const float n1 = gx1 * gx1 + gy1 * gy1 + NGF_EPS;
            const float cross = gx0 * gx1 + gy0 * gy1;
            s += cross * cross * __frcp_rn(n0 * n1);   // dot^2 = cross^2/(n0*n1)
        }
    }

    // wave64 reduce -> LDS -> one partial per block
#pragma unroll
    for (int off = 32; off > 0; off >>= 1) s += __shfl_down(s, off, 64);

    __shared__ float lds[4];
    if (lane == 0) lds[wave] = s;
    __syncthreads();
    if (threadIdx.x == 0)
        partials[blockIdx.x] = lds[0] + lds[1] + lds[2] + lds[3];
}

// 4096 partials: one float4 per thread, 1024 threads, one block.
__global__ __launch_bounds__(1024) void ngf_finalize(const float4* __restrict__ partials,
                                                     float inv_n,
                                                     float* __restrict__ out) {
    const float4 v = partials[threadIdx.x];
    float s = v.x + v.y + v.z + v.w;
#pragma unroll
    for (int off = 32; off > 0; off >>= 1) s += __shfl_down(s, off, 64);

    __shared__ float lds[16];
    const int wave = threadIdx.x >> 6;
    const int lane = threadIdx.x & 63;
    if (lane == 0) lds[wave] = s;
    __syncthreads();
    if (threadIdx.x == 0) {
        float tot = 0.f;
#pragma unroll
        for (int i = 0; i < 16; ++i) tot += lds[i];
        out[0] = 1.0f - tot * inv_n;
    }
}

extern "C" void kernel_launch(void* const* d_in, const int* in_sizes, int n_in,
                              void* d_out, int out_size, void* d_ws, size_t ws_size,
                              hipStream_t stream) {
    const float* I0 = (const float*)d_in[0];
    const float* I1 = (const float*)d_in[1];
    float* partials = (float*)d_ws;

    const int N        = in_sizes[0];          // 16,777,216
    const int nthreads = N / 16;               // 16 px per thread
    const int nblocks  = nthreads / 256;       // 4096

    ngf_partial<<<nblocks, 256, 0, stream>>>(I0, I1, partials);
    ngf_finalize<<<1, 1024, 0, stream>>>((const float4*)partials,
                                         1.0f / (float)N, (float*)d_out);
}

// Round 4
// 142.309 us; speedup vs baseline: 1.1536x; 1.0071x over previous
//
#include <hip/hip_runtime.h>

// NGF loss: g = normalized gradient (central diff interior, one-sided at edges),
// loss = 1 - mean( (g0 . g1)^2 ).  B=64, C=1, H=512, W=512, fp32.
//
// R4: global_load_lds DMA staging (m97 pattern). R2/R3 showed the compiler
// serializes register loads (VGPR=40 => ~2-3 in flight) and the kernel runs
// 43us whether fed from HBM or L3 => L2-latency-bound serialization. DMA
// staging keeps in-flight data out of VGPRs; full 512-wide rows in LDS make
// all boundary handling simple index clamps (no shuffles, no divergence).

#define HH 512
#define WW 512
#define NGF_EPS 1e-10f
#define RROWS 8            // compute rows per block
#define WROWS (RROWS + 2)  // staged rows per image (halo above/below)

typedef const __attribute__((address_space(1))) void global_cv;
typedef __attribute__((address_space(3))) void lds_v;

__device__ __forceinline__ float get(const float4& v, int i) {
    return i == 0 ? v.x : i == 1 ? v.y : i == 2 ? v.z : v.w;
}

// grid = 64 imgs * 64 row-blocks = 4096 blocks x 256 threads
__global__ __launch_bounds__(256, 4) void ngf_partial(const float* __restrict__ I0,
                                                      const float* __restrict__ I1,
                                                      float* __restrict__ partials) {
    __shared__ float smem[2 * WROWS * WW];   // 40 KB -> 4 blocks/CU

    const int tid  = threadIdx.x;
    const int img  = blockIdx.x >> 6;
    const int rb   = blockIdx.x & 63;
    const int h0   = rb * RROWS;
    const int wave = tid >> 6;
    const int lane = tid & 63;

    const float* p0 = I0 + (size_t)img * (HH * WW);
    const float* p1 = I1 + (size_t)img * (HH * WW);

    // Stage rows clamp(h0-1 .. h0+8) of both images: 2*10 rows * 2KB = 40
    // chunks of 1KB (64 lanes x 16B). Wave v issues chunks v, v+4, ..., v+36.
    // LDS row j holds global row clamp(h0-1+j) => all H-boundary cases are
    // automatically the reference's forward/backward diffs.
#pragma unroll
    for (int it = 0; it < 10; ++it) {
        const int q  = wave + it * 4;        // 0..39
        const int x  = q & 1;                // half-row (256 floats)
        const int jm = q >> 1;               // 0..19
        const int m  = (jm >= WROWS) ? 1 : 0;
        const int j  = jm - m * WROWS;       // staged row 0..9
        int grow = h0 - 1 + j;
        grow = grow < 0 ? 0 : (grow > HH - 1 ? HH - 1 : grow);
        const float* src = (m ? p1 : p0) + grow * WW + x * 256 + lane * 4;
        float* dst = smem + (m * WROWS + j) * WW + x * 256;   // wave-uniform
        __builtin_amdgcn_global_load_lds((global_cv*)src, (lds_v*)dst, 16, 0, 0);
    }
    __syncthreads();   // compiler emits vmcnt(0) drain before the barrier

    // Compute: 8 rows x 128 col-groups = 1024 groups, 4 per thread.
    float s = 0.f;
#pragma unroll
    for (int k = 0; k < 4; ++k) {
        const int g = k * 256 + tid;
        const int r = g >> 7;                 // local row 0..7
        const int w = (g & 127) << 2;         // col 0..508
        const float* s0 = smem + r * WW;              // img0: row r = up-halo
        const float* s1 = smem + (WROWS + r) * WW;    // img1

        const float4 u0 = *(const float4*)(s0 + w);
        const float4 c0 = *(const float4*)(s0 + WW + w);
        const float4 d0 = *(const float4*)(s0 + 2 * WW + w);
        const float  l0 = (w > 0)      ? s0[WW + w - 1] : c0.x;
        const float  q0 = (w < WW - 4) ? s0[WW + w + 4] : c0.w;

        const float4 u1 = *(const float4*)(s1 + w);
        const float4 c1 = *(const float4*)(s1 + WW + w);
        const float4 d1 = *(const float4*)(s1 + 2 * WW + w);
        const float  l1 = (w > 0)      ? s1[WW + w - 1] : c1.x;
        const float  q1 = (w < WW - 4) ? s1[WW + w + 4] : c1.w;

#pragma unroll
        for (int i = 0; i < 4; ++i) {
            const float gx0 = get(d0, i) - get(u0, i);
            const float gx1 = get(d1, i) - get(u1, i);
            const float am0 = (i == 0) ? l0 : get(c0, i - 1);
            const float ap0 = (i == 3) ? q0 : get(c0, i + 1);
            const float am1 = (i == 0) ? l1 : get(c1, i - 1);
            const float ap1 = (i == 3) ? q1 : get(c1, i + 1);
            const float gy0 = ap0 - am0;
            const float gy1 = ap1 - am1;
            const float n0 = gx0 * gx0 + gy0 * gy0 + NGF_EPS;
            const float n1 = gx1 * gx1 + gy1 * gy1 + NGF_EPS;
            const float cross = gx0 * gx1 + gy0 * gy1;
            s += cross * cross * __frcp_rn(n0 * n1);  // dot^2 = cross^2/(n0*n1)
        }
    }

    // wave64 reduce -> LDS -> one partial per block
#pragma unroll
    for (int off = 32; off > 0; off >>= 1) s += __shfl_down(s, off, 64);

    __shared__ float red[4];
    if (lane == 0) red[wave] = s;
    __syncthreads();
    if (tid == 0)
        partials[blockIdx.x] = red[0] + red[1] + red[2] + red[3];
}

// 4096 partials: one float4 per thread, 1024 threads, one block.
__global__ __launch_bounds__(1024) void ngf_finalize(const float4* __restrict__ partials,
                                                     float inv_n,
                                                     float* __restrict__ out) {
    const float4 v = partials[threadIdx.x];
    float s = v.x + v.y + v.z + v.w;
#pragma unroll
    for (int off = 32; off > 0; off >>= 1) s += __shfl_down(s, off, 64);

    __shared__ float lds[16];
    const int wave = threadIdx.x >> 6;
    const int lane = threadIdx.x & 63;
    if (lane == 0) lds[wave] = s;
    __syncthreads();
    if (threadIdx.x == 0) {
        float tot = 0.f;
#pragma unroll
        for (int i = 0; i < 16; ++i) tot += lds[i];
        out[0] = 1.0f - tot * inv_n;
    }
}

extern "C" void kernel_launch(void* const* d_in, const int* in_sizes, int n_in,
                              void* d_out, int out_size, void* d_ws, size_t ws_size,
                              hipStream_t stream) {
    const float* I0 = (const float*)d_in[0];
    const float* I1 = (const float*)d_in[1];
    float* partials = (float*)d_ws;

    const int N = in_sizes[0];                 // 16,777,216
    const int nblocks = 64 * (HH / RROWS);     // 4096

    ngf_partial<<<nblocks, 256, 0, stream>>>(I0, I1, partials);
    ngf_finalize<<<1, 1024, 0, stream>>>((const float4*)partials,
                                         1.0f / (float)N, (float*)d_out);
}